// Round 9
// baseline (390.035 us; speedup 1.0000x reference)
//
#include <hip/hip_runtime.h>
#include <hip/hip_bf16.h>
#include <cstdint>

// ---------------------------------------------------------------------------
// Model: h=relu(x@W1+b1); h=AGNN(h,beta=1); h=AGNN(h,beta2); h=relu(h@W2+b2);
//        out = concat(segmax(h,batch), segmean(h,batch)) @ W3 + b3
// N=30000, E=480000, F_IN=1280, H=512, H2=256, G=64, C=10
// bf16 rows through propagation; 64x256 4-wave MFMA GEMM tiles (4 blocks/CU
// co-residency -> independent barrier domains hide stage stalls);
// XOR-swizzled LDS; DPP wave reduction + 2-deep gather prefetch in AGNN.
// ---------------------------------------------------------------------------

typedef __attribute__((ext_vector_type(8))) short bf16x8;
typedef __attribute__((ext_vector_type(4))) float f32x4;
typedef __attribute__((ext_vector_type(8))) unsigned short ushort8;
typedef __attribute__((ext_vector_type(4))) unsigned short ushort4v;
typedef __attribute__((ext_vector_type(4))) unsigned int uint4v;

__device__ inline unsigned short f2bf(float f) {
    unsigned int u = __float_as_uint(f);
    u += 0x7FFFu + ((u >> 16) & 1u);   // RNE
    return (unsigned short)(u >> 16);
}

__device__ __forceinline__ float bf2f(unsigned short u) {
    return __uint_as_float(((unsigned int)u) << 16);
}

// packed f32x2 -> bf16x2 (RNE), single HW instruction on gfx950
__device__ __forceinline__ unsigned int cvtpk(float lo, float hi) {
    unsigned int r;
    asm("v_cvt_pk_bf16_f32 %0, %1, %2" : "=v"(r) : "v"(lo), "v"(hi));
    return r;
}

__device__ __forceinline__ void gload_lds16(const void* g, void* l) {
    __builtin_amdgcn_global_load_lds(
        (const __attribute__((address_space(1))) void*)g,
        (__attribute__((address_space(3))) void*)l, 16, 0, 0);
}

// ---- wave64 sum via DPP (VALU pipe, no ds_bpermute). Result uniform. ------
__device__ __forceinline__ float wave_sum_dpp(float p) {
    int t;
    t = __builtin_amdgcn_update_dpp(0, __float_as_int(p), 0xB1, 0xf, 0xf, true);  // quad_perm [1,0,3,2]
    p += __int_as_float(t);
    t = __builtin_amdgcn_update_dpp(0, __float_as_int(p), 0x4E, 0xf, 0xf, true);  // quad_perm [2,3,0,1]
    p += __int_as_float(t);
    t = __builtin_amdgcn_update_dpp(0, __float_as_int(p), 0x141, 0xf, 0xf, true); // row_half_mirror
    p += __int_as_float(t);
    t = __builtin_amdgcn_update_dpp(0, __float_as_int(p), 0x140, 0xf, 0xf, true); // row_mirror
    p += __int_as_float(t);
    t = __builtin_amdgcn_update_dpp(0, __float_as_int(p), 0x142, 0xf, 0xf, true); // row_bcast15
    p += __int_as_float(t);
    t = __builtin_amdgcn_update_dpp(0, __float_as_int(p), 0x143, 0xf, 0xf, true); // row_bcast31
    p += __int_as_float(t);
    return __int_as_float(__builtin_amdgcn_readlane(__float_as_int(p), 63));
}

// ---- tiled transpose: W [K][N] f32 -> Wt [N][K] bf16 (K,N multiples of 32) -
__global__ __launch_bounds__(256) void k_transpose_bf16(
    const float* __restrict__ W, unsigned short* __restrict__ Wt, int K, int N) {
    __shared__ unsigned short t[32][33];
    int k0 = blockIdx.x * 32, n0 = blockIdx.y * 32;
    int tr = threadIdx.x >> 3;          // 0..31
    int tc = (threadIdx.x & 7) * 4;     // 0,4,...,28
    float4 v = *(const float4*)(W + (long)(k0 + tr) * N + n0 + tc);
    t[tr][tc + 0] = f2bf(v.x); t[tr][tc + 1] = f2bf(v.y);
    t[tr][tc + 2] = f2bf(v.z); t[tr][tc + 3] = f2bf(v.w);
    __syncthreads();
    ushort4v o = { t[tc + 0][tr], t[tc + 1][tr], t[tc + 2][tr], t[tc + 3][tr] };
    *(ushort4v*)(Wt + (long)(n0 + tr) * K + k0 + tc) = o;
}

// ---- MFMA GEMM: C[M][N] = relu(A[M][K] @ Bt[N][K]^T + bias) ---------------
// Block tile 64 x 256, 256 threads = 4 waves (2m x 2n), wave tile 32x128
// (acc[2][8]), BK=32. Double-buffered LDS (40 KB) -> 4 blocks/CU; grid
// (M/64, NOUT/256) = ~938 blocks -> ~3.7 independent barrier domains per CU
// whose staging stalls interleave (the round-6 2-phase schedule, which beat
// both counted-vmcnt variants, now with 2x the co-residency).
// LDS rows 64B; 16B granule g of row r at slot g ^ ((r>>1)&3) (conflict-free,
// both sides: pre-swizzled global source / swizzled ds addrs).
// AF32: A f32 in global, reg-staged + packed to bf16 (swizzled ds_write).
template <int K, int NOUT, bool AF32, bool OUTBF16>
__global__ __launch_bounds__(256, 4) void k_gemm_bias_relu(
    const void* __restrict__ Av, const unsigned short* __restrict__ Bt,
    const float* __restrict__ bias, void* __restrict__ Cv, int M) {
    constexpr int NS = K / 32;
    __shared__ unsigned short As[2][64 * 32];
    __shared__ unsigned short Bs[2][256 * 32];
    int tid = threadIdx.x;
    int w = tid >> 6, l = tid & 63;
    int wm = w >> 1, wn = w & 1;
    int mBase = blockIdx.x * 64;
    int nBase = blockIdx.y * 256;

    const float* Af = (const float*)Av;
    const unsigned short* Ab = (const unsigned short*)Av;

    // AF32 reg-staging: thread owns 8 consecutive f32 of one row (4 thr/row)
    int arow = tid >> 2;                          // 0..63
    int aslot = (tid & 3) ^ ((arow >> 1) & 3);    // swizzled 16B slot
    long aRowG = mBase + arow; if (aRowG >= M) aRowG = M - 1;
    const float* aptr = AF32 ? (Af + aRowG * K + (tid & 3) * 8) : nullptr;

    auto stageB = [&](int b, int k0) {
#pragma unroll
        for (int o = 0; o < 4; ++o) {
            int rbase = (o * 4 + w) * 16;                // wave-uniform
            int row = rbase + (l >> 2);                  // local B row
            int gsrc = (l & 3) ^ ((row >> 1) & 3);       // pre-swizzled src
            gload_lds16(Bt + (long)(nBase + row) * K + k0 + gsrc * 8,
                        &Bs[b][rbase * 32]);
        }
    };
    auto stageAbf = [&](int b, int k0) {
        int rbase = w * 16;
        int row = rbase + (l >> 2);
        int gsrc = (l & 3) ^ ((row >> 1) & 3);
        long gr = mBase + row; if (gr >= M) gr = M - 1;
        gload_lds16(Ab + gr * K + k0 + gsrc * 8, &As[b][rbase * 32]);
    };

    f32x4 acc[2][8] = {};

    // ---- prologue: stage k0 = 0 into buffer 0 -----------------------------
    stageB(0, 0);
    if constexpr (AF32) {
        float4 f0 = *(const float4*)(aptr);
        float4 f1 = *(const float4*)(aptr + 4);
        uint4v p = { cvtpk(f0.x, f0.y), cvtpk(f0.z, f0.w),
                     cvtpk(f1.x, f1.y), cvtpk(f1.z, f1.w) };
        *(uint4v*)(&As[0][arow * 32 + aslot * 8]) = p;
    } else {
        stageAbf(0, 0);
    }
    __syncthreads();

    int s = 0;
    for (int step = 0; step < NS; ++step, s ^= 1) {
        int nk = (step + 1) * 32;
        float4 f0, f1;
        if (nk < K) {                      // issue next-tile loads FIRST
            stageB(s ^ 1, nk);
            if constexpr (AF32) {
                f0 = *(const float4*)(aptr + nk);
                f1 = *(const float4*)(aptr + nk + 4);
            } else {
                stageAbf(s ^ 1, nk);
            }
        }
        // ---- compute current buffer (swizzled reads) ----------------------
        bf16x8 af[2];
#pragma unroll
        for (int m = 0; m < 2; ++m) {
            int ra = wm * 32 + m * 16 + (l & 15);
            int g = (l >> 4) ^ ((ra >> 1) & 3);
            af[m] = *(const bf16x8*)(&As[s][ra * 32 + g * 8]);
        }
#pragma unroll
        for (int n = 0; n < 8; ++n) {
            int rb = wn * 128 + n * 16 + (l & 15);
            int g = (l >> 4) ^ ((rb >> 1) & 3);
            bf16x8 bfr = *(const bf16x8*)(&Bs[s][rb * 32 + g * 8]);
#pragma unroll
            for (int m = 0; m < 2; ++m)
                acc[m][n] = __builtin_amdgcn_mfma_f32_16x16x32_bf16(
                    af[m], bfr, acc[m][n], 0, 0, 0);
        }
        if constexpr (AF32) {
            if (nk < K) {                    // write next A after MFMAs
                uint4v p = { cvtpk(f0.x, f0.y), cvtpk(f0.z, f0.w),
                             cvtpk(f1.x, f1.y), cvtpk(f1.z, f1.w) };
                *(uint4v*)(&As[s ^ 1][arow * 32 + aslot * 8]) = p;
            }
        }
        __syncthreads();
    }

    // ---- epilogue: row=(l>>4)*4+r, col=l&15 (HW-verified) -----------------
#pragma unroll
    for (int m = 0; m < 2; ++m) {
        int row = mBase + wm * 32 + m * 16 + (l >> 4) * 4;
#pragma unroll
        for (int n = 0; n < 8; ++n) {
            int colg = nBase + wn * 128 + n * 16 + (l & 15);
            float bv = bias[colg];
#pragma unroll
            for (int r = 0; r < 4; ++r) {
                if (row + r < M) {
                    float v = fmaxf(acc[m][n][r] + bv, 0.f);
                    if constexpr (OUTBF16)
                        ((unsigned short*)Cv)[(long)(row + r) * NOUT + colg] = f2bf(v);
                    else
                        ((float*)Cv)[(long)(row + r) * NOUT + colg] = v;
                }
            }
        }
    }
}

// ---- CSR build ------------------------------------------------------------
__global__ void k_csr_init(int* __restrict__ cnt, int* __restrict__ fill, int n) {
    int i = blockIdx.x * blockDim.x + threadIdx.x;
    if (i < n) { cnt[i] = 1; fill[i] = 0; }   // 1 = self loop
}

__global__ void k_csr_count(const int* __restrict__ ei, int* __restrict__ cnt, int E) {
    int e = blockIdx.x * blockDim.x + threadIdx.x;
    if (e < E) atomicAdd(&cnt[ei[E + e]], 1);   // dst row
}

// hierarchical exclusive scan: phase 1 (per-1024-chunk scan + chunk total)
__global__ __launch_bounds__(1024) void k_scan1(const int* __restrict__ cnt,
                                                int* __restrict__ rowp,
                                                int* __restrict__ bsum, int n) {
    __shared__ int wsum[16];
    int b = blockIdx.x, t = threadIdx.x, lane = t & 63, w = t >> 6;
    int i = b * 1024 + t;
    int v = (i < n) ? cnt[i] : 0;
    int x = v;
#pragma unroll
    for (int off = 1; off < 64; off <<= 1) {
        int y = __shfl_up(x, off, 64);
        if (lane >= off) x += y;
    }
    if (lane == 63) wsum[w] = x;
    __syncthreads();
    if (t < 16) {
        int s = wsum[t];
#pragma unroll
        for (int off = 1; off < 16; off <<= 1) {
            int y = __shfl_up(s, off, 64);
            if (t >= off) s += y;
        }
        wsum[t] = s;
    }
    __syncthreads();
    int wo = w ? wsum[w - 1] : 0;
    if (i < n) rowp[i] = wo + x - v;            // chunk-local exclusive
    if (t == 0) bsum[b] = wsum[15];             // chunk total
}

// phase 2: exclusive scan of <=64 chunk totals (single wave)
__global__ __launch_bounds__(64) void k_scan2(int* __restrict__ bsum, int nb) {
    int lane = threadIdx.x;
    int v = (lane < nb) ? bsum[lane] : 0;
    int x = v;
#pragma unroll
    for (int off = 1; off < 64; off <<= 1) {
        int y = __shfl_up(x, off, 64);
        if (lane >= off) x += y;
    }
    int total = __shfl(x, nb - 1, 64);
    if (lane < nb) bsum[lane] = x - v;          // exclusive
    if (lane == 0) bsum[nb] = total;
}

// phase 3: add chunk offsets; write rowp[n] = total
__global__ __launch_bounds__(1024) void k_scan3(const int* __restrict__ bsum,
                                                int* __restrict__ rowp, int n, int nb) {
    int i = blockIdx.x * 1024 + threadIdx.x;
    if (i < n) rowp[i] += bsum[i >> 10];
    else if (i == n) rowp[n] = bsum[nb];
}

__global__ void k_csr_fill(const int* __restrict__ ei, const int* __restrict__ rowp,
                           int* __restrict__ fill, int* __restrict__ col, int E, int n) {
    int idx = blockIdx.x * blockDim.x + threadIdx.x;
    if (idx < E) {
        int d = ei[E + idx];
        int s = ei[idx];
        int pos = atomicAdd(&fill[d], 1);
        col[rowp[d] + pos] = s;
    } else if (idx < E + n) {
        int nd = idx - E;
        int pos = atomicAdd(&fill[nd], 1);
        col[rowp[nd] + pos] = nd;   // self loop
    }
}

// ---- row inverse L2 norm, bf16 rows (H=512) --------------------------------
__global__ __launch_bounds__(256) void k_norm_bf16(const unsigned short* __restrict__ h,
                                                   float* __restrict__ invn, int n) {
    int row = blockIdx.x * 4 + (threadIdx.x >> 6);
    int lane = threadIdx.x & 63;
    if (row >= n) return;
    ushort8 v = *(const ushort8*)(h + (long)row * 512 + lane * 8);
    float s = 0.f;
#pragma unroll
    for (int e = 0; e < 8; ++e) { float f = bf2f(v[e]); s += f * f; }
    s = wave_sum_dpp(s);
    if (lane == 0) invn[row] = 1.f / fmaxf(sqrtf(s), 1e-12f);
}

// ---- AGNN propagation: bf16 rows, one wave per dst, single-pass -----------
// 2-deep source-row prefetch (2 gathers in flight on the L2/L3 path);
// DPP wave reduce; readlane broadcasts. Optionally fuses output inv-norm.
__global__ __launch_bounds__(256) void k_agnn(
    const unsigned short* __restrict__ h, const float* __restrict__ invn,
    const int* __restrict__ rowp, const int* __restrict__ col,
    const float* __restrict__ beta_ptr, unsigned short* __restrict__ out,
    float* __restrict__ invn_out, int nNodes) {
    int dst = blockIdx.x * 4 + (threadIdx.x >> 6);
    int lane = threadIdx.x & 63;
    if (dst >= nNodes) return;
    float beta = beta_ptr ? beta_ptr[0] : 1.0f;
    ushort8 hdv = *(const ushort8*)(h + (long)dst * 512 + lane * 8);
    float hd[8];
#pragma unroll
    for (int e = 0; e < 8; ++e) hd[e] = bf2f(hdv[e]);
    float coef = beta * invn[dst];
    int s0 = rowp[dst], s1 = rowp[dst + 1];

    float m = -1e30f, ssum = 0.f;
    float acc[8] = {0.f, 0.f, 0.f, 0.f, 0.f, 0.f, 0.f, 0.f};

    for (int base = s0; base < s1; base += 64) {
        int cnt = min(s1 - base, 64);
        int gi = base + lane; if (gi >= s1) gi = s1 - 1;
        int idxl = col[gi];              // batch of up to 64 edge indices
        float vinl = invn[idxl];         // batch of src inv-norms
        ushort8 nxt = *(const ushort8*)(
            h + (long)__builtin_amdgcn_readlane(idxl, 0) * 512 + lane * 8);
        ushort8 nxt2 = {};
        if (cnt > 1)
            nxt2 = *(const ushort8*)(
                h + (long)__builtin_amdgcn_readlane(idxl, 1) * 512 + lane * 8);
        for (int j = 0; j < cnt; ++j) {
            ushort8 cur = nxt;
            nxt = nxt2;
            if (j + 2 < cnt) {
                int sn = __builtin_amdgcn_readlane(idxl, j + 2);
                nxt2 = *(const ushort8*)(h + (long)sn * 512 + lane * 8);  // prefetch
            }
            float a[8];
#pragma unroll
            for (int e = 0; e < 8; ++e) a[e] = bf2f(cur[e]);
            float p = a[0] * hd[0] + a[1] * hd[1] + a[2] * hd[2] + a[3] * hd[3] +
                      a[4] * hd[4] + a[5] * hd[5] + a[6] * hd[6] + a[7] * hd[7];
            p = wave_sum_dpp(p);         // uniform across wave
            float vin_j = __int_as_float(
                __builtin_amdgcn_readlane(__float_as_int(vinl), j));
            float alpha = coef * vin_j * p;
            if (alpha > m) {             // wave-uniform
                float sc = __expf(m - alpha);
                ssum *= sc;
#pragma unroll
                for (int e = 0; e < 8; ++e) acc[e] *= sc;
                m = alpha;
            }
            float wgt = __expf(alpha - m);
            ssum += wgt;
#pragma unroll
            for (int e = 0; e < 8; ++e) acc[e] += wgt * a[e];
        }
    }
    float inv_s = 1.f / ssum;
#pragma unroll
    for (int e = 0; e < 8; ++e) acc[e] *= inv_s;

    uint4v o = { cvtpk(acc[0], acc[1]), cvtpk(acc[2], acc[3]),
                 cvtpk(acc[4], acc[5]), cvtpk(acc[6], acc[7]) };
    *(uint4v*)(out + (long)dst * 512 + lane * 8) = o;

    if (invn_out) {                      // fused output norm (feeds next prop)
        float s = 0.f;
#pragma unroll
        for (int e = 0; e < 8; ++e) s += acc[e] * acc[e];
        s = wave_sum_dpp(s);
        if (lane == 0) invn_out[dst] = 1.f / fmaxf(sqrtf(s), 1e-12f);
    }
}

// ---- graph boundaries in sorted batch -------------------------------------
__global__ void k_bounds(const int* __restrict__ batch, int* __restrict__ starts,
                         int n, int G) {
    int g = blockIdx.x * blockDim.x + threadIdx.x;
    if (g > G) return;
    int lo = 0, hi = n;
    while (lo < hi) {
        int mid = (lo + hi) >> 1;
        if (batch[mid] < g) lo = mid + 1; else hi = mid;
    }
    starts[g] = lo;
}

// ---- per-graph max/mean pool (H2=256) -------------------------------------
__global__ __launch_bounds__(256) void k_pool(const float* __restrict__ h3,
                                              const int* __restrict__ starts,
                                              float* __restrict__ pooled) {
    int g = blockIdx.x;
    int t = threadIdx.x;
    int s = starts[g], e = starts[g + 1];
    float mx = -3.402823466e38f, sm = 0.f;
    int r = s;
    for (; r + 4 <= e; r += 4) {          // ILP unroll
        float v0 = h3[(long)(r + 0) * 256 + t];
        float v1 = h3[(long)(r + 1) * 256 + t];
        float v2 = h3[(long)(r + 2) * 256 + t];
        float v3 = h3[(long)(r + 3) * 256 + t];
        mx = fmaxf(mx, fmaxf(fmaxf(v0, v1), fmaxf(v2, v3)));
        sm += (v0 + v1) + (v2 + v3);
    }
    for (; r < e; ++r) {
        float v = h3[(long)r * 256 + t];
        mx = fmaxf(mx, v); sm += v;
    }
    float cnt = fmaxf((float)(e - s), 1.f);
    pooled[g * 512 + t] = mx;
    pooled[g * 512 + 256 + t] = sm / cnt;
}

// ---- final tiny GEMM: out[G][C] = pooled[G][512] @ W3[512][C] + b3 --------
__global__ __launch_bounds__(64) void k_final(const float* __restrict__ pooled,
                                              const float* __restrict__ W3,
                                              const float* __restrict__ b3,
                                              float* __restrict__ out, int C) {
    int g = blockIdx.x;
    int lane = threadIdx.x;
    for (int c = 0; c < C; c++) {
        float p = 0.f;
        for (int k = lane; k < 512; k += 64) p += pooled[g * 512 + k] * W3[k * C + c];
#pragma unroll
        for (int off = 32; off; off >>= 1) p += __shfl_xor(p, off, 64);
        if (lane == 0) out[g * C + c] = p + b3[c];
    }
}

// ---------------------------------------------------------------------------
extern "C" void kernel_launch(void* const* d_in, const int* in_sizes, int n_in,
                              void* d_out, int out_size, void* d_ws, size_t ws_size,
                              hipStream_t stream) {
    const float* x     = (const float*)d_in[0];
    const int*   ei    = (const int*)d_in[1];
    const int*   batch = (const int*)d_in[2];
    const float* W1    = (const float*)d_in[3];
    const float* b1    = (const float*)d_in[4];
    const float* beta2 = (const float*)d_in[5];
    const float* W2    = (const float*)d_in[6];
    const float* b2    = (const float*)d_in[7];
    const float* W3    = (const float*)d_in[8];
    const float* b3    = (const float*)d_in[9];
    float* out = (float*)d_out;

    const int N = in_sizes[2];          // 30000
    const int E = in_sizes[1] / 2;      // 480000
    const int F_IN = in_sizes[0] / N;   // 1280
    const int H = in_sizes[4];          // 512
    const int H2 = in_sizes[7];         // 256
    const int C = in_sizes[9];          // 10
    const int G = out_size / C;         // 64

    char* ws = (char*)d_ws;
    unsigned short* H1B = (unsigned short*)(ws + 0);            // 30.72 MB bf16
    unsigned short* HPB = (unsigned short*)(ws + 31000000L);    // 30.72 MB bf16
    unsigned short* H2B = (unsigned short*)(ws + 62000000L);    // 30.72 MB bf16
    float*          H3  = (float*)(ws + 0);                     // 61.44 MB f32 (over H1B/HPB, both dead)
    unsigned short* W1T = (unsigned short*)(ws + 93000000L);    // 1.31 MB
    unsigned short* W2T = (unsigned short*)(ws + 94500000L);    // 0.26 MB
    float* INVN_A = (float*)(ws + 95000000L);                   // 120 KB
    float* INVN_B = (float*)(ws + 95200000L);                   // 120 KB
    int*   CNT    = (int*)(ws + 95400000L);
    int*   FILL   = (int*)(ws + 95600000L);
    int*   ROWP   = (int*)(ws + 95800000L);
    int*   COL    = (int*)(ws + 96000000L);                     // 2.04 MB
    int*   BSUM   = (int*)(ws + 98100000L);
    int*   START  = (int*)(ws + 98110000L);
    float* POOLED = (float*)(ws + 98120000L);                   // 131 KB

    // 1. weight transposes (f32 -> bf16 [N][K])
    { dim3 g1(F_IN / 32, H / 32); k_transpose_bf16<<<g1, 256, 0, stream>>>(W1, W1T, F_IN, H); }
    { dim3 g2(H / 32, H2 / 32);   k_transpose_bf16<<<g2, 256, 0, stream>>>(W2, W2T, H, H2); }

    // 2. CSR (incoming edges + self loops)
    int nb = (N + 1023) / 1024;   // 30
    k_csr_init<<<(N + 255) / 256, 256, 0, stream>>>(CNT, FILL, N);
    k_csr_count<<<(E + 255) / 256, 256, 0, stream>>>(ei, CNT, E);
    k_scan1<<<nb, 1024, 0, stream>>>(CNT, ROWP, BSUM, N);
    k_scan2<<<1, 64, 0, stream>>>(BSUM, nb);
    k_scan3<<<(N + 1 + 1023) / 1024, 1024, 0, stream>>>(BSUM, ROWP, N, nb);
    k_csr_fill<<<(E + N + 255) / 256, 256, 0, stream>>>(ei, ROWP, FILL, COL, E, N);

    // 3. GEMM1: H1B = bf16(relu(x @ W1 + b1))  [N,512]; 64x256 tiles
    {
        dim3 grid((N + 63) / 64, H / 256);
        k_gemm_bias_relu<1280, 512, true, true>
            <<<grid, 256, 0, stream>>>(x, W1T, b1, H1B, N);
    }

    // 4. prop1 (beta=1): HPB = AGNN(H1B), fused invn of HPB -> INVN_B
    k_norm_bf16<<<(N + 3) / 4, 256, 0, stream>>>(H1B, INVN_A, N);
    k_agnn<<<(N + 3) / 4, 256, 0, stream>>>(H1B, INVN_A, ROWP, COL, nullptr, HPB, INVN_B, N);

    // 5. prop2 (beta=beta2): H2B = AGNN(HPB)
    k_agnn<<<(N + 3) / 4, 256, 0, stream>>>(HPB, INVN_B, ROWP, COL, beta2, H2B, nullptr, N);

    // 6. GEMM2: H3 = relu(H2B @ W2 + b2)  [N,256] f32; 64x256 tiles
    {
        dim3 grid((N + 63) / 64, 1);
        k_gemm_bias_relu<512, 256, false, false>
            <<<grid, 256, 0, stream>>>(H2B, W2T, b2, H3, N);
    }

    // 7. pool + final linear
    k_bounds<<<1, 128, 0, stream>>>(batch, START, N, G);
    k_pool<<<G, 256, 0, stream>>>(H3, START, POOLED);
    k_final<<<G, 64, 0, stream>>>(POOLED, W3, b3, out, C);
}

// Round 10
// 379.280 us; speedup vs baseline: 1.0284x; 1.0284x over previous
//
#include <hip/hip_runtime.h>
#include <hip/hip_bf16.h>
#include <cstdint>

// ---------------------------------------------------------------------------
// Model: h=relu(x@W1+b1); h=AGNN(h,beta=1); h=AGNN(h,beta2); h=relu(h@W2+b2);
//        out = concat(segmax(h,batch), segmean(h,batch)) @ W3 + b3
// N=30000, E=480000, F_IN=1280, H=512, H2=256, G=64, C=10
// bf16 rows through propagation; 128x256 8-wave MFMA GEMMs (round-6 proven
// config) with depth-2 f32-A register staging; XOR-swizzled LDS; AGNN with
// fixed-shift softmax (no online rescale: |alpha| <= |beta|), 2-edge ILP,
// 4-deep gather prefetch, DPP wave reduction.
// ---------------------------------------------------------------------------

typedef __attribute__((ext_vector_type(8))) short bf16x8;
typedef __attribute__((ext_vector_type(4))) float f32x4;
typedef __attribute__((ext_vector_type(8))) unsigned short ushort8;
typedef __attribute__((ext_vector_type(4))) unsigned short ushort4v;
typedef __attribute__((ext_vector_type(4))) unsigned int uint4v;

__device__ inline unsigned short f2bf(float f) {
    unsigned int u = __float_as_uint(f);
    u += 0x7FFFu + ((u >> 16) & 1u);   // RNE
    return (unsigned short)(u >> 16);
}

__device__ __forceinline__ float bf2f(unsigned short u) {
    return __uint_as_float(((unsigned int)u) << 16);
}

// packed f32x2 -> bf16x2 (RNE), single HW instruction on gfx950
__device__ __forceinline__ unsigned int cvtpk(float lo, float hi) {
    unsigned int r;
    asm("v_cvt_pk_bf16_f32 %0, %1, %2" : "=v"(r) : "v"(lo), "v"(hi));
    return r;
}

__device__ __forceinline__ void gload_lds16(const void* g, void* l) {
    __builtin_amdgcn_global_load_lds(
        (const __attribute__((address_space(1))) void*)g,
        (__attribute__((address_space(3))) void*)l, 16, 0, 0);
}

// ---- wave64 sum via DPP (VALU pipe, no ds_bpermute). Result uniform. ------
__device__ __forceinline__ float wave_sum_dpp(float p) {
    int t;
    t = __builtin_amdgcn_update_dpp(0, __float_as_int(p), 0xB1, 0xf, 0xf, true);  // quad_perm [1,0,3,2]
    p += __int_as_float(t);
    t = __builtin_amdgcn_update_dpp(0, __float_as_int(p), 0x4E, 0xf, 0xf, true);  // quad_perm [2,3,0,1]
    p += __int_as_float(t);
    t = __builtin_amdgcn_update_dpp(0, __float_as_int(p), 0x141, 0xf, 0xf, true); // row_half_mirror
    p += __int_as_float(t);
    t = __builtin_amdgcn_update_dpp(0, __float_as_int(p), 0x140, 0xf, 0xf, true); // row_mirror
    p += __int_as_float(t);
    t = __builtin_amdgcn_update_dpp(0, __float_as_int(p), 0x142, 0xf, 0xf, true); // row_bcast15
    p += __int_as_float(t);
    t = __builtin_amdgcn_update_dpp(0, __float_as_int(p), 0x143, 0xf, 0xf, true); // row_bcast31
    p += __int_as_float(t);
    return __int_as_float(__builtin_amdgcn_readlane(__float_as_int(p), 63));
}

// ---- tiled transpose: W [K][N] f32 -> Wt [N][K] bf16 (K,N multiples of 32) -
__global__ __launch_bounds__(256) void k_transpose_bf16(
    const float* __restrict__ W, unsigned short* __restrict__ Wt, int K, int N) {
    __shared__ unsigned short t[32][33];
    int k0 = blockIdx.x * 32, n0 = blockIdx.y * 32;
    int tr = threadIdx.x >> 3;          // 0..31
    int tc = (threadIdx.x & 7) * 4;     // 0,4,...,28
    float4 v = *(const float4*)(W + (long)(k0 + tr) * N + n0 + tc);
    t[tr][tc + 0] = f2bf(v.x); t[tr][tc + 1] = f2bf(v.y);
    t[tr][tc + 2] = f2bf(v.z); t[tr][tc + 3] = f2bf(v.w);
    __syncthreads();
    ushort4v o = { t[tc + 0][tr], t[tc + 1][tr], t[tc + 2][tr], t[tc + 3][tr] };
    *(ushort4v*)(Wt + (long)(n0 + tr) * K + k0 + tc) = o;
}

// ---- MFMA GEMM: C[M][N] = relu(A[M][K] @ Bt[N][K]^T + bias) ---------------
// Round-6 proven config: block tile 128 x BN (BN=256), 512 threads = 8 waves
// (2m x 4n), wave tile 64x64 (acc[4][4]), BK=32, double-buffered LDS (48 KB),
// one __syncthreads per K-step, next-tile loads issued before the MFMAs.
// NEW vs round 6: depth-2 f32-A register chain — at step t we LOAD A(t+2)
// and WRITE A(t+1) from regs loaded at step t-1, so the ds_write's implicit
// wait sees >= 1 full K-step + this step's MFMA of latency cover (round 6
// gave it only ~300 cyc for ~900 cyc HBM latency).
// LDS rows 64B; 16B granule g of row r at slot g ^ ((r>>1)&3) (conflict-free,
// both sides: pre-swizzled global source / swizzled ds addrs).
template <int K, int BN, int NOUT, bool AF32, bool OUTBF16>
__global__ __launch_bounds__(512, 4) void k_gemm_bias_relu(
    const void* __restrict__ Av, const unsigned short* __restrict__ Bt,
    const float* __restrict__ bias, void* __restrict__ Cv, int M) {
    constexpr int NSTEP = K / 32;
    __shared__ unsigned short As[2][128 * 32];
    __shared__ unsigned short Bs[2][BN * 32];
    int tid = threadIdx.x;
    int w = tid >> 6, l = tid & 63;
    int wm = w >> 2, wn = w & 3;
    int mBase = blockIdx.x * 128;
    int nBase = blockIdx.y * BN;

    const float* Af = (const float*)Av;
    const unsigned short* Ab = (const unsigned short*)Av;

    // AF32 reg-staging: thread owns 8 consecutive f32 of one row (4 thr/row)
    int arow = tid >> 2;                          // 0..127
    int aslot = (tid & 3) ^ ((arow >> 1) & 3);    // swizzled 16B slot
    long aRowG = mBase + arow; if (aRowG >= M) aRowG = M - 1;
    const float* aptr = AF32 ? (Af + aRowG * K + (tid & 3) * 8) : nullptr;

    auto stageB = [&](int b, int k0) {
#pragma unroll
        for (int o = 0; o < BN / 128; ++o) {
            int rbase = (w * (BN / 128) + o) * 16;       // wave-uniform
            int row = rbase + (l >> 2);                  // local B row
            int gsrc = (l & 3) ^ ((row >> 1) & 3);       // pre-swizzled src
            gload_lds16(Bt + (long)(nBase + row) * K + k0 + gsrc * 8,
                        &Bs[b][rbase * 32]);
        }
    };
    auto stageAbf = [&](int b, int k0) {
        int rbase = w * 16;
        int row = rbase + (l >> 2);
        int gsrc = (l & 3) ^ ((row >> 1) & 3);
        long gr = mBase + row; if (gr >= M) gr = M - 1;
        gload_lds16(Ab + gr * K + k0 + gsrc * 8, &As[b][rbase * 32]);
    };

    f32x4 acc[4][4] = {};
    float4 Aw0 = {}, Aw1 = {}, An0 = {}, An1 = {};

    // ---- prologue: stage k-tile 0 into buffer 0; preload A(1) f32 ---------
    stageB(0, 0);
    if constexpr (AF32) {
        float4 z0 = *(const float4*)(aptr);
        float4 z1 = *(const float4*)(aptr + 4);
        uint4v p = { cvtpk(z0.x, z0.y), cvtpk(z0.z, z0.w),
                     cvtpk(z1.x, z1.y), cvtpk(z1.z, z1.w) };
        *(uint4v*)(&As[0][arow * 32 + aslot * 8]) = p;
        if (NSTEP > 1) {
            Aw0 = *(const float4*)(aptr + 32);
            Aw1 = *(const float4*)(aptr + 36);
        }
    } else {
        stageAbf(0, 0);
    }
    __syncthreads();

    int s = 0;
    for (int step = 0; step < NSTEP; ++step, s ^= 1) {
        int nk = (step + 1) * 32;
        int nk2 = (step + 2) * 32;
        if (nk < K) {                      // issue next-tile B (and bf16-A)
            stageB(s ^ 1, nk);
            if constexpr (!AF32) stageAbf(s ^ 1, nk);
        }
        if constexpr (AF32) {
            if (nk2 < K) {                 // issue A(t+2) f32 -> regs
                An0 = *(const float4*)(aptr + nk2);
                An1 = *(const float4*)(aptr + nk2 + 4);
            }
        }
        // ---- compute current buffer (swizzled reads) ----------------------
        bf16x8 af[4];
#pragma unroll
        for (int m = 0; m < 4; ++m) {
            int ra = wm * 64 + m * 16 + (l & 15);
            int g = (l >> 4) ^ ((ra >> 1) & 3);
            af[m] = *(const bf16x8*)(&As[s][ra * 32 + g * 8]);
        }
#pragma unroll
        for (int n = 0; n < 4; ++n) {
            int rb = wn * 64 + n * 16 + (l & 15);
            int g = (l >> 4) ^ ((rb >> 1) & 3);
            bf16x8 bfr = *(const bf16x8*)(&Bs[s][rb * 32 + g * 8]);
#pragma unroll
            for (int m = 0; m < 4; ++m)
                acc[m][n] = __builtin_amdgcn_mfma_f32_16x16x32_bf16(
                    af[m], bfr, acc[m][n], 0, 0, 0);
        }
        if constexpr (AF32) {
            if (nk < K) {                  // write A(t+1) from regs of t-1
                uint4v p = { cvtpk(Aw0.x, Aw0.y), cvtpk(Aw0.z, Aw0.w),
                             cvtpk(Aw1.x, Aw1.y), cvtpk(Aw1.z, Aw1.w) };
                *(uint4v*)(&As[s ^ 1][arow * 32 + aslot * 8]) = p;
                Aw0 = An0; Aw1 = An1;
            }
        }
        __syncthreads();
    }

    // ---- epilogue: row=(l>>4)*4+r, col=l&15 (HW-verified) -----------------
#pragma unroll
    for (int m = 0; m < 4; ++m) {
        int row = mBase + wm * 64 + m * 16 + (l >> 4) * 4;
#pragma unroll
        for (int n = 0; n < 4; ++n) {
            int colg = nBase + wn * 64 + n * 16 + (l & 15);
            float bv = bias[colg];
#pragma unroll
            for (int r = 0; r < 4; ++r) {
                if (row + r < M) {
                    float v = fmaxf(acc[m][n][r] + bv, 0.f);
                    if constexpr (OUTBF16)
                        ((unsigned short*)Cv)[(long)(row + r) * NOUT + colg] = f2bf(v);
                    else
                        ((float*)Cv)[(long)(row + r) * NOUT + colg] = v;
                }
            }
        }
    }
}

// ---- CSR build ------------------------------------------------------------
__global__ void k_csr_init(int* __restrict__ cnt, int* __restrict__ fill, int n) {
    int i = blockIdx.x * blockDim.x + threadIdx.x;
    if (i < n) { cnt[i] = 1; fill[i] = 0; }   // 1 = self loop
}

__global__ void k_csr_count(const int* __restrict__ ei, int* __restrict__ cnt, int E) {
    int e = blockIdx.x * blockDim.x + threadIdx.x;
    if (e < E) atomicAdd(&cnt[ei[E + e]], 1);   // dst row
}

// hierarchical exclusive scan: phase 1 (per-1024-chunk scan + chunk total)
__global__ __launch_bounds__(1024) void k_scan1(const int* __restrict__ cnt,
                                                int* __restrict__ rowp,
                                                int* __restrict__ bsum, int n) {
    __shared__ int wsum[16];
    int b = blockIdx.x, t = threadIdx.x, lane = t & 63, w = t >> 6;
    int i = b * 1024 + t;
    int v = (i < n) ? cnt[i] : 0;
    int x = v;
#pragma unroll
    for (int off = 1; off < 64; off <<= 1) {
        int y = __shfl_up(x, off, 64);
        if (lane >= off) x += y;
    }
    if (lane == 63) wsum[w] = x;
    __syncthreads();
    if (t < 16) {
        int s = wsum[t];
#pragma unroll
        for (int off = 1; off < 16; off <<= 1) {
            int y = __shfl_up(s, off, 64);
            if (t >= off) s += y;
        }
        wsum[t] = s;
    }
    __syncthreads();
    int wo = w ? wsum[w - 1] : 0;
    if (i < n) rowp[i] = wo + x - v;            // chunk-local exclusive
    if (t == 0) bsum[b] = wsum[15];             // chunk total
}

// phase 2: exclusive scan of <=64 chunk totals (single wave)
__global__ __launch_bounds__(64) void k_scan2(int* __restrict__ bsum, int nb) {
    int lane = threadIdx.x;
    int v = (lane < nb) ? bsum[lane] : 0;
    int x = v;
#pragma unroll
    for (int off = 1; off < 64; off <<= 1) {
        int y = __shfl_up(x, off, 64);
        if (lane >= off) x += y;
    }
    int total = __shfl(x, nb - 1, 64);
    if (lane < nb) bsum[lane] = x - v;          // exclusive
    if (lane == 0) bsum[nb] = total;
}

// phase 3: add chunk offsets; write rowp[n] = total
__global__ __launch_bounds__(1024) void k_scan3(const int* __restrict__ bsum,
                                                int* __restrict__ rowp, int n, int nb) {
    int i = blockIdx.x * 1024 + threadIdx.x;
    if (i < n) rowp[i] += bsum[i >> 10];
    else if (i == n) rowp[n] = bsum[nb];
}

__global__ void k_csr_fill(const int* __restrict__ ei, const int* __restrict__ rowp,
                           int* __restrict__ fill, int* __restrict__ col, int E, int n) {
    int idx = blockIdx.x * blockDim.x + threadIdx.x;
    if (idx < E) {
        int d = ei[E + idx];
        int s = ei[idx];
        int pos = atomicAdd(&fill[d], 1);
        col[rowp[d] + pos] = s;
    } else if (idx < E + n) {
        int nd = idx - E;
        int pos = atomicAdd(&fill[nd], 1);
        col[rowp[nd] + pos] = nd;   // self loop
    }
}

// ---- row inverse L2 norm, bf16 rows (H=512) --------------------------------
__global__ __launch_bounds__(256) void k_norm_bf16(const unsigned short* __restrict__ h,
                                                   float* __restrict__ invn, int n) {
    int row = blockIdx.x * 4 + (threadIdx.x >> 6);
    int lane = threadIdx.x & 63;
    if (row >= n) return;
    ushort8 v = *(const ushort8*)(h + (long)row * 512 + lane * 8);
    float s = 0.f;
#pragma unroll
    for (int e = 0; e < 8; ++e) { float f = bf2f(v[e]); s += f * f; }
    s = wave_sum_dpp(s);
    if (lane == 0) invn[row] = 1.f / fmaxf(sqrtf(s), 1e-12f);
}

// ---- AGNN propagation: bf16 rows, one wave per dst, single-pass -----------
// Fixed-shift softmax: alpha = beta*cos(theta) is bounded by |beta|*(1+eps)
// a priori, so exp(alpha - 1.0625|beta|) never overflows and softmax's shift
// invariance makes the result exact -- NO online max tracking / rescale.
// 2-edge interleave (independent accE/accO + dual DPP chains), 4-deep row
// prefetch. Optionally fuses the inv-L2-norm of the OUTPUT row.
__global__ __launch_bounds__(256) void k_agnn(
    const unsigned short* __restrict__ h, const float* __restrict__ invn,
    const int* __restrict__ rowp, const int* __restrict__ col,
    const float* __restrict__ beta_ptr, unsigned short* __restrict__ out,
    float* __restrict__ invn_out, int nNodes) {
    int dst = blockIdx.x * 4 + (threadIdx.x >> 6);
    int lane = threadIdx.x & 63;
    if (dst >= nNodes) return;
    float beta = beta_ptr ? beta_ptr[0] : 1.0f;
    ushort8 hdv = *(const ushort8*)(h + (long)dst * 512 + lane * 8);
    float hd[8];
#pragma unroll
    for (int e = 0; e < 8; ++e) hd[e] = bf2f(hdv[e]);
    float coef = beta * invn[dst];
    float mshift = fabsf(beta) * 1.0625f;   // >= max possible alpha (incl. bf16 eps)
    int s0 = rowp[dst], s1 = rowp[dst + 1];

    float ssum = 0.f;
    float accE[8] = {0.f, 0.f, 0.f, 0.f, 0.f, 0.f, 0.f, 0.f};
    float accO[8] = {0.f, 0.f, 0.f, 0.f, 0.f, 0.f, 0.f, 0.f};

    for (int base = s0; base < s1; base += 64) {
        int cnt = min(s1 - base, 64);
        int gi = base + lane; if (gi >= s1) gi = s1 - 1;
        int idxl = col[gi];              // batch of up to 64 edge indices
        float vinl = invn[idxl];         // batch of src inv-norms
        ushort8 r0 = {}, r1 = {}, r2 = {}, r3 = {};
        r0 = *(const ushort8*)(h + (long)__builtin_amdgcn_readlane(idxl, 0) * 512 + lane * 8);
        if (cnt > 1) r1 = *(const ushort8*)(h + (long)__builtin_amdgcn_readlane(idxl, 1) * 512 + lane * 8);
        if (cnt > 2) r2 = *(const ushort8*)(h + (long)__builtin_amdgcn_readlane(idxl, 2) * 512 + lane * 8);
        if (cnt > 3) r3 = *(const ushort8*)(h + (long)__builtin_amdgcn_readlane(idxl, 3) * 512 + lane * 8);
        int j = 0;
        for (; j + 1 < cnt; j += 2) {
            ushort8 c0 = r0, c1 = r1;
            r0 = r2; r1 = r3;
            if (j + 4 < cnt) r2 = *(const ushort8*)(h + (long)__builtin_amdgcn_readlane(idxl, j + 4) * 512 + lane * 8);
            if (j + 5 < cnt) r3 = *(const ushort8*)(h + (long)__builtin_amdgcn_readlane(idxl, j + 5) * 512 + lane * 8);
            float a0[8], a1[8];
#pragma unroll
            for (int e = 0; e < 8; ++e) { a0[e] = bf2f(c0[e]); a1[e] = bf2f(c1[e]); }
            float p0 = a0[0] * hd[0] + a0[1] * hd[1] + a0[2] * hd[2] + a0[3] * hd[3] +
                       a0[4] * hd[4] + a0[5] * hd[5] + a0[6] * hd[6] + a0[7] * hd[7];
            float p1 = a1[0] * hd[0] + a1[1] * hd[1] + a1[2] * hd[2] + a1[3] * hd[3] +
                       a1[4] * hd[4] + a1[5] * hd[5] + a1[6] * hd[6] + a1[7] * hd[7];
            p0 = wave_sum_dpp(p0);       // two independent chains interleave
            p1 = wave_sum_dpp(p1);
            float al0 = coef * __int_as_float(__builtin_amdgcn_readlane(__float_as_int(vinl), j)) * p0;
            float al1 = coef * __int_as_float(__builtin_amdgcn_readlane(__float_as_int(vinl), j + 1)) * p1;
            float w0 = __expf(al0 - mshift);
            float w1 = __expf(al1 - mshift);
            ssum += w0 + w1;
#pragma unroll
            for (int e = 0; e < 8; ++e) { accE[e] += w0 * a0[e]; accO[e] += w1 * a1[e]; }
        }
        if (j < cnt) {                   // odd tail
            float a0[8];
#pragma unroll
            for (int e = 0; e < 8; ++e) a0[e] = bf2f(r0[e]);
            float p0 = a0[0] * hd[0] + a0[1] * hd[1] + a0[2] * hd[2] + a0[3] * hd[3] +
                       a0[4] * hd[4] + a0[5] * hd[5] + a0[6] * hd[6] + a0[7] * hd[7];
            p0 = wave_sum_dpp(p0);
            float al0 = coef * __int_as_float(__builtin_amdgcn_readlane(__float_as_int(vinl), j)) * p0;
            float w0 = __expf(al0 - mshift);
            ssum += w0;
#pragma unroll
            for (int e = 0; e < 8; ++e) accE[e] += w0 * a0[e];
        }
    }
    float inv_s = 1.f / ssum;
    float acc[8];
#pragma unroll
    for (int e = 0; e < 8; ++e) acc[e] = (accE[e] + accO[e]) * inv_s;

    uint4v o = { cvtpk(acc[0], acc[1]), cvtpk(acc[2], acc[3]),
                 cvtpk(acc[4], acc[5]), cvtpk(acc[6], acc[7]) };
    *(uint4v*)(out + (long)dst * 512 + lane * 8) = o;

    if (invn_out) {                      // fused output norm (feeds next prop)
        float s = 0.f;
#pragma unroll
        for (int e = 0; e < 8; ++e) s += acc[e] * acc[e];
        s = wave_sum_dpp(s);
        if (lane == 0) invn_out[dst] = 1.f / fmaxf(sqrtf(s), 1e-12f);
    }
}

// ---- graph boundaries in sorted batch -------------------------------------
__global__ void k_bounds(const int* __restrict__ batch, int* __restrict__ starts,
                         int n, int G) {
    int g = blockIdx.x * blockDim.x + threadIdx.x;
    if (g > G) return;
    int lo = 0, hi = n;
    while (lo < hi) {
        int mid = (lo + hi) >> 1;
        if (batch[mid] < g) lo = mid + 1; else hi = mid;
    }
    starts[g] = lo;
}

// ---- per-graph max/mean pool (H2=256) -------------------------------------
__global__ __launch_bounds__(256) void k_pool(const float* __restrict__ h3,
                                              const int* __restrict__ starts,
                                              float* __restrict__ pooled) {
    int g = blockIdx.x;
    int t = threadIdx.x;
    int s = starts[g], e = starts[g + 1];
    float mx = -3.402823466e38f, sm = 0.f;
    int r = s;
    for (; r + 4 <= e; r += 4) {          // ILP unroll
        float v0 = h3[(long)(r + 0) * 256 + t];
        float v1 = h3[(long)(r + 1) * 256 + t];
        float v2 = h3[(long)(r + 2) * 256 + t];
        float v3 = h3[(long)(r + 3) * 256 + t];
        mx = fmaxf(mx, fmaxf(fmaxf(v0, v1), fmaxf(v2, v3)));
        sm += (v0 + v1) + (v2 + v3);
    }
    for (; r < e; ++r) {
        float v = h3[(long)r * 256 + t];
        mx = fmaxf(mx, v); sm += v;
    }
    float cnt = fmaxf((float)(e - s), 1.f);
    pooled[g * 512 + t] = mx;
    pooled[g * 512 + 256 + t] = sm / cnt;
}

// ---- final tiny GEMM: out[G][C] = pooled[G][512] @ W3[512][C] + b3 --------
__global__ __launch_bounds__(64) void k_final(const float* __restrict__ pooled,
                                              const float* __restrict__ W3,
                                              const float* __restrict__ b3,
                                              float* __restrict__ out, int C) {
    int g = blockIdx.x;
    int lane = threadIdx.x;
    for (int c = 0; c < C; c++) {
        float p = 0.f;
        for (int k = lane; k < 512; k += 64) p += pooled[g * 512 + k] * W3[k * C + c];
#pragma unroll
        for (int off = 32; off; off >>= 1) p += __shfl_xor(p, off, 64);
        if (lane == 0) out[g * C + c] = p + b3[c];
    }
}

// ---------------------------------------------------------------------------
extern "C" void kernel_launch(void* const* d_in, const int* in_sizes, int n_in,
                              void* d_out, int out_size, void* d_ws, size_t ws_size,
                              hipStream_t stream) {
    const float* x     = (const float*)d_in[0];
    const int*   ei    = (const int*)d_in[1];
    const int*   batch = (const int*)d_in[2];
    const float* W1    = (const float*)d_in[3];
    const float* b1    = (const float*)d_in[4];
    const float* beta2 = (const float*)d_in[5];
    const float* W2    = (const float*)d_in[6];
    const float* b2    = (const float*)d_in[7];
    const float* W3    = (const float*)d_in[8];
    const float* b3    = (const float*)d_in[9];
    float* out = (float*)d_out;

    const int N = in_sizes[2];          // 30000
    const int E = in_sizes[1] / 2;      // 480000
    const int F_IN = in_sizes[0] / N;   // 1280
    const int H = in_sizes[4];          // 512
    const int H2 = in_sizes[7];         // 256
    const int C = in_sizes[9];          // 10
    const int G = out_size / C;         // 64

    char* ws = (char*)d_ws;
    unsigned short* H1B = (unsigned short*)(ws + 0);            // 30.72 MB bf16
    unsigned short* HPB = (unsigned short*)(ws + 31000000L);    // 30.72 MB bf16
    unsigned short* H2B = (unsigned short*)(ws + 62000000L);    // 30.72 MB bf16
    float*          H3  = (float*)(ws + 0);                     // 61.44 MB f32 (over H1B/HPB, both dead)
    unsigned short* W1T = (unsigned short*)(ws + 93000000L);    // 1.31 MB
    unsigned short* W2T = (unsigned short*)(ws + 94500000L);    // 0.26 MB
    float* INVN_A = (float*)(ws + 95000000L);                   // 120 KB
    float* INVN_B = (float*)(ws + 95200000L);                   // 120 KB
    int*   CNT    = (int*)(ws + 95400000L);
    int*   FILL   = (int*)(ws + 95600000L);
    int*   ROWP   = (int*)(ws + 95800000L);
    int*   COL    = (int*)(ws + 96000000L);                     // 2.04 MB
    int*   BSUM   = (int*)(ws + 98100000L);
    int*   START  = (int*)(ws + 98110000L);
    float* POOLED = (float*)(ws + 98120000L);                   // 131 KB

    // 1. weight transposes (f32 -> bf16 [N][K])
    { dim3 g1(F_IN / 32, H / 32); k_transpose_bf16<<<g1, 256, 0, stream>>>(W1, W1T, F_IN, H); }
    { dim3 g2(H / 32, H2 / 32);   k_transpose_bf16<<<g2, 256, 0, stream>>>(W2, W2T, H, H2); }

    // 2. CSR (incoming edges + self loops)
    int nb = (N + 1023) / 1024;   // 30
    k_csr_init<<<(N + 255) / 256, 256, 0, stream>>>(CNT, FILL, N);
    k_csr_count<<<(E + 255) / 256, 256, 0, stream>>>(ei, CNT, E);
    k_scan1<<<nb, 1024, 0, stream>>>(CNT, ROWP, BSUM, N);
    k_scan2<<<1, 64, 0, stream>>>(BSUM, nb);
    k_scan3<<<(N + 1 + 1023) / 1024, 1024, 0, stream>>>(BSUM, ROWP, N, nb);
    k_csr_fill<<<(E + N + 255) / 256, 256, 0, stream>>>(ei, ROWP, FILL, COL, E, N);

    // 3. GEMM1: H1B = bf16(relu(x @ W1 + b1))  [N,512]; 128x256 tiles
    {
        dim3 grid((N + 127) / 128, H / 256);
        k_gemm_bias_relu<1280, 256, 512, true, true>
            <<<grid, 512, 0, stream>>>(x, W1T, b1, H1B, N);
    }

    // 4. prop1 (beta=1): HPB = AGNN(H1B), fused invn of HPB -> INVN_B
    k_norm_bf16<<<(N + 3) / 4, 256, 0, stream>>>(H1B, INVN_A, N);
    k_agnn<<<(N + 3) / 4, 256, 0, stream>>>(H1B, INVN_A, ROWP, COL, nullptr, HPB, INVN_B, N);

    // 5. prop2 (beta=beta2): H2B = AGNN(HPB)
    k_agnn<<<(N + 3) / 4, 256, 0, stream>>>(HPB, INVN_B, ROWP, COL, beta2, H2B, nullptr, N);

    // 6. GEMM2: H3 = relu(H2B @ W2 + b2)  [N,256] f32; BN=256 read-once A
    {
        dim3 grid((N + 127) / 128, 1);
        k_gemm_bias_relu<512, 256, 256, false, false>
            <<<grid, 512, 0, stream>>>(H2B, W2T, b2, H3, N);
    }

    // 7. pool + final linear
    k_bounds<<<1, 128, 0, stream>>>(batch, START, N, G);
    k_pool<<<G, 256, 0, stream>>>(H3, START, POOLED);
    k_final<<<G, 64, 0, stream>>>(POOLED, W3, b3, out, C);
}

// Round 11
// 353.074 us; speedup vs baseline: 1.1047x; 1.0742x over previous
//
#include <hip/hip_runtime.h>
#include <hip/hip_bf16.h>
#include <cstdint>

// ---------------------------------------------------------------------------
// Model: h=relu(x@W1+b1); h=AGNN(h,beta=1); h=AGNN(h,beta2); h=relu(h@W2+b2);
//        out = concat(segmax(h,batch), segmean(h,batch)) @ W3 + b3
// N=30000, E=480000, F_IN=1280, H=512, H2=256, G=64, C=10
// bf16 rows everywhere after GEMM1; round-6-proven 8-wave 2-phase MFMA GEMM
// (BN generalized: GEMM1 128x256, GEMM2 128x128 for 2x co-residency);
// XOR-swizzled LDS; AGNN fixed-shift softmax + 2-edge ILP + DPP reduce;
// fused bounds->pool, scan2->scan3, merged transposes (13 kernels).
// ---------------------------------------------------------------------------

typedef __attribute__((ext_vector_type(8))) short bf16x8;
typedef __attribute__((ext_vector_type(4))) float f32x4;
typedef __attribute__((ext_vector_type(8))) unsigned short ushort8;
typedef __attribute__((ext_vector_type(4))) unsigned short ushort4v;
typedef __attribute__((ext_vector_type(4))) unsigned int uint4v;

__device__ inline unsigned short f2bf(float f) {
    unsigned int u = __float_as_uint(f);
    u += 0x7FFFu + ((u >> 16) & 1u);   // RNE
    return (unsigned short)(u >> 16);
}

__device__ __forceinline__ float bf2f(unsigned short u) {
    return __uint_as_float(((unsigned int)u) << 16);
}

// packed f32x2 -> bf16x2 (RNE), single HW instruction on gfx950
__device__ __forceinline__ unsigned int cvtpk(float lo, float hi) {
    unsigned int r;
    asm("v_cvt_pk_bf16_f32 %0, %1, %2" : "=v"(r) : "v"(lo), "v"(hi));
    return r;
}

__device__ __forceinline__ void gload_lds16(const void* g, void* l) {
    __builtin_amdgcn_global_load_lds(
        (const __attribute__((address_space(1))) void*)g,
        (__attribute__((address_space(3))) void*)l, 16, 0, 0);
}

// ---- wave64 sum via DPP (VALU pipe, no ds_bpermute). Result uniform. ------
__device__ __forceinline__ float wave_sum_dpp(float p) {
    int t;
    t = __builtin_amdgcn_update_dpp(0, __float_as_int(p), 0xB1, 0xf, 0xf, true);  // quad_perm [1,0,3,2]
    p += __int_as_float(t);
    t = __builtin_amdgcn_update_dpp(0, __float_as_int(p), 0x4E, 0xf, 0xf, true);  // quad_perm [2,3,0,1]
    p += __int_as_float(t);
    t = __builtin_amdgcn_update_dpp(0, __float_as_int(p), 0x141, 0xf, 0xf, true); // row_half_mirror
    p += __int_as_float(t);
    t = __builtin_amdgcn_update_dpp(0, __float_as_int(p), 0x140, 0xf, 0xf, true); // row_mirror
    p += __int_as_float(t);
    t = __builtin_amdgcn_update_dpp(0, __float_as_int(p), 0x142, 0xf, 0xf, true); // row_bcast15
    p += __int_as_float(t);
    t = __builtin_amdgcn_update_dpp(0, __float_as_int(p), 0x143, 0xf, 0xf, true); // row_bcast31
    p += __int_as_float(t);
    return __int_as_float(__builtin_amdgcn_readlane(__float_as_int(p), 63));
}

// ---- merged tiled transpose: both weights in one launch -------------------
// W [K][N] f32 -> Wt [N][K] bf16 (K,N multiples of 32)
__global__ __launch_bounds__(256) void k_transpose_both(
    const float* __restrict__ W1, unsigned short* __restrict__ W1T,
    int K1, int N1, int nt1,
    const float* __restrict__ W2, unsigned short* __restrict__ W2T,
    int K2, int N2) {
    __shared__ unsigned short tb[32][33];
    int id = blockIdx.x;
    const float* W; unsigned short* Wt; int K, N, bx, by;
    if (id < nt1) {
        W = W1; Wt = W1T; K = K1; N = N1;
        int nx = K1 / 32; bx = id % nx; by = id / nx;
    } else {
        id -= nt1;
        W = W2; Wt = W2T; K = K2; N = N2;
        int nx = K2 / 32; bx = id % nx; by = id / nx;
    }
    int k0 = bx * 32, n0 = by * 32;
    int tr = threadIdx.x >> 3;          // 0..31
    int tc = (threadIdx.x & 7) * 4;     // 0,4,...,28
    float4 v = *(const float4*)(W + (long)(k0 + tr) * N + n0 + tc);
    tb[tr][tc + 0] = f2bf(v.x); tb[tr][tc + 1] = f2bf(v.y);
    tb[tr][tc + 2] = f2bf(v.z); tb[tr][tc + 3] = f2bf(v.w);
    __syncthreads();
    ushort4v o = { tb[tc + 0][tr], tb[tc + 1][tr], tb[tc + 2][tr], tb[tc + 3][tr] };
    *(ushort4v*)(Wt + (long)(n0 + tr) * K + k0 + tc) = o;
}

// ---- MFMA GEMM: C[M][N] = relu(A[M][K] @ Bt[N][K]^T + bias) ---------------
// Round-6 proven schedule: block tile 128 x BN, 512 threads = 8 waves
// (2m x 4n), wave tile 64 x BN/4 (acc[4][BN/64]), BK=32, double-buffered
// LDS, ONE __syncthreads per K-step; next-tile loads issued before the MFMAs
// (the MFMA block itself is the latency cover for the in-step f32-A loads).
// LDS rows 64B; 16B granule g of row r at slot g ^ ((r>>1)&3) (conflict-free,
// both sides: pre-swizzled global source / swizzled ds addrs).
// AF32: A f32 in global, reg-staged in-step + packed to bf16 (swizzled write).
template <int K, int BN, int NOUT, bool AF32, bool OUTBF16>
__global__ __launch_bounds__(512, 4) void k_gemm_bias_relu(
    const void* __restrict__ Av, const unsigned short* __restrict__ Bt,
    const float* __restrict__ bias, void* __restrict__ Cv, int M) {
    constexpr int NSTEP = K / 32;
    constexpr int NF = BN / 64;          // n-frags per wave
    __shared__ unsigned short As[2][128 * 32];
    __shared__ unsigned short Bs[2][BN * 32];
    int tid = threadIdx.x;
    int w = tid >> 6, l = tid & 63;
    int wm = w >> 2, wn = w & 3;
    int mBase = blockIdx.x * 128;
    int nBase = blockIdx.y * BN;

    const float* Af = (const float*)Av;
    const unsigned short* Ab = (const unsigned short*)Av;

    // AF32 reg-staging: thread owns 8 consecutive f32 of one row (4 thr/row)
    int arow = tid >> 2;                          // 0..127
    int aslot = (tid & 3) ^ ((arow >> 1) & 3);    // swizzled 16B slot
    long aRowG = mBase + arow; if (aRowG >= M) aRowG = M - 1;
    const float* aptr = AF32 ? (Af + aRowG * K + (tid & 3) * 8) : nullptr;

    auto stageB = [&](int b, int k0) {
#pragma unroll
        for (int o = 0; o < BN / 128; ++o) {
            int rbase = (w * (BN / 128) + o) * 16;       // wave-uniform
            int row = rbase + (l >> 2);                  // local B row
            int gsrc = (l & 3) ^ ((row >> 1) & 3);       // pre-swizzled src
            gload_lds16(Bt + (long)(nBase + row) * K + k0 + gsrc * 8,
                        &Bs[b][rbase * 32]);
        }
    };
    auto stageAbf = [&](int b, int k0) {
        int rbase = w * 16;
        int row = rbase + (l >> 2);
        int gsrc = (l & 3) ^ ((row >> 1) & 3);
        long gr = mBase + row; if (gr >= M) gr = M - 1;
        gload_lds16(Ab + gr * K + k0 + gsrc * 8, &As[b][rbase * 32]);
    };

    f32x4 acc[4][NF] = {};

    // ---- prologue: stage k-tile 0 into buffer 0 ---------------------------
    stageB(0, 0);
    if constexpr (AF32) {
        float4 z0 = *(const float4*)(aptr);
        float4 z1 = *(const float4*)(aptr + 4);
        uint4v p = { cvtpk(z0.x, z0.y), cvtpk(z0.z, z0.w),
                     cvtpk(z1.x, z1.y), cvtpk(z1.z, z1.w) };
        *(uint4v*)(&As[0][arow * 32 + aslot * 8]) = p;
    } else {
        stageAbf(0, 0);
    }
    __syncthreads();

    int s = 0;
    for (int step = 0; step < NSTEP; ++step, s ^= 1) {
        int nk = (step + 1) * 32;
        float4 f0, f1;
        if (nk < K) {                      // issue next-tile loads FIRST
            stageB(s ^ 1, nk);
            if constexpr (AF32) {
                f0 = *(const float4*)(aptr + nk);
                f1 = *(const float4*)(aptr + nk + 4);
            } else {
                stageAbf(s ^ 1, nk);
            }
        }
        // ---- compute current buffer (swizzled reads) ----------------------
        bf16x8 af[4];
#pragma unroll
        for (int m = 0; m < 4; ++m) {
            int ra = wm * 64 + m * 16 + (l & 15);
            int g = (l >> 4) ^ ((ra >> 1) & 3);
            af[m] = *(const bf16x8*)(&As[s][ra * 32 + g * 8]);
        }
#pragma unroll
        for (int n = 0; n < NF; ++n) {
            int rb = wn * (BN / 4) + n * 16 + (l & 15);
            int g = (l >> 4) ^ ((rb >> 1) & 3);
            bf16x8 bfr = *(const bf16x8*)(&Bs[s][rb * 32 + g * 8]);
#pragma unroll
            for (int m = 0; m < 4; ++m)
                acc[m][n] = __builtin_amdgcn_mfma_f32_16x16x32_bf16(
                    af[m], bfr, acc[m][n], 0, 0, 0);
        }
        if constexpr (AF32) {
            if (nk < K) {                    // write next A after MFMAs
                uint4v p = { cvtpk(f0.x, f0.y), cvtpk(f0.z, f0.w),
                             cvtpk(f1.x, f1.y), cvtpk(f1.z, f1.w) };
                *(uint4v*)(&As[s ^ 1][arow * 32 + aslot * 8]) = p;
            }
        }
        __syncthreads();
    }

    // ---- epilogue: row=(l>>4)*4+r, col=l&15 (HW-verified) -----------------
#pragma unroll
    for (int m = 0; m < 4; ++m) {
        int row = mBase + wm * 64 + m * 16 + (l >> 4) * 4;
#pragma unroll
        for (int n = 0; n < NF; ++n) {
            int colg = nBase + wn * (BN / 4) + n * 16 + (l & 15);
            float bv = bias[colg];
#pragma unroll
            for (int r = 0; r < 4; ++r) {
                if (row + r < M) {
                    float v = fmaxf(acc[m][n][r] + bv, 0.f);
                    if constexpr (OUTBF16)
                        ((unsigned short*)Cv)[(long)(row + r) * NOUT + colg] = f2bf(v);
                    else
                        ((float*)Cv)[(long)(row + r) * NOUT + colg] = v;
                }
            }
        }
    }
}

// ---- CSR build ------------------------------------------------------------
__global__ void k_csr_init(int* __restrict__ cnt, int* __restrict__ fill, int n) {
    int i = blockIdx.x * blockDim.x + threadIdx.x;
    if (i < n) { cnt[i] = 1; fill[i] = 0; }   // 1 = self loop
}

__global__ void k_csr_count(const int* __restrict__ ei, int* __restrict__ cnt, int E) {
    int e = blockIdx.x * blockDim.x + threadIdx.x;
    if (e < E) atomicAdd(&cnt[ei[E + e]], 1);   // dst row
}

// hierarchical exclusive scan: phase 1 (per-1024-chunk scan + chunk total)
__global__ __launch_bounds__(1024) void k_scan1(const int* __restrict__ cnt,
                                                int* __restrict__ rowp,
                                                int* __restrict__ bsum, int n) {
    __shared__ int wsum[16];
    int b = blockIdx.x, t = threadIdx.x, lane = t & 63, w = t >> 6;
    int i = b * 1024 + t;
    int v = (i < n) ? cnt[i] : 0;
    int x = v;
#pragma unroll
    for (int off = 1; off < 64; off <<= 1) {
        int y = __shfl_up(x, off, 64);
        if (lane >= off) x += y;
    }
    if (lane == 63) wsum[w] = x;
    __syncthreads();
    if (t < 16) {
        int s = wsum[t];
#pragma unroll
        for (int off = 1; off < 16; off <<= 1) {
            int y = __shfl_up(s, off, 64);
            if (t >= off) s += y;
        }
        wsum[t] = s;
    }
    __syncthreads();
    int wo = w ? wsum[w - 1] : 0;
    if (i < n) rowp[i] = wo + x - v;            // chunk-local exclusive
    if (t == 0) bsum[b] = wsum[15];             // chunk total
}

// phase 2+3 fused: every block redundantly wave-scans the <=64 chunk totals,
// then adds its chunk offset; rowp[n] = grand total.
__global__ __launch_bounds__(1024) void k_scan23(const int* __restrict__ bsum,
                                                 int* __restrict__ rowp, int n, int nb) {
    __shared__ int off[65];
    int t = threadIdx.x;
    if (t < 64) {
        int v = (t < nb) ? bsum[t] : 0;
        int x = v;
#pragma unroll
        for (int o = 1; o < 64; o <<= 1) {
            int y = __shfl_up(x, o, 64);
            if (t >= o) x += y;
        }
        off[t] = x - v;                    // exclusive
        if (t == nb - 1) off[64] = x;      // total
    }
    __syncthreads();
    int i = blockIdx.x * 1024 + t;
    if (i < n) rowp[i] += off[i >> 10];
    else if (i == n) rowp[n] = off[64];
}

__global__ void k_csr_fill(const int* __restrict__ ei, const int* __restrict__ rowp,
                           int* __restrict__ fill, int* __restrict__ col, int E, int n) {
    int idx = blockIdx.x * blockDim.x + threadIdx.x;
    if (idx < E) {
        int d = ei[E + idx];
        int s = ei[idx];
        int pos = atomicAdd(&fill[d], 1);
        col[rowp[d] + pos] = s;
    } else if (idx < E + n) {
        int nd = idx - E;
        int pos = atomicAdd(&fill[nd], 1);
        col[rowp[nd] + pos] = nd;   // self loop
    }
}

// ---- row inverse L2 norm, bf16 rows (H=512) --------------------------------
__global__ __launch_bounds__(256) void k_norm_bf16(const unsigned short* __restrict__ h,
                                                   float* __restrict__ invn, int n) {
    int row = blockIdx.x * 4 + (threadIdx.x >> 6);
    int lane = threadIdx.x & 63;
    if (row >= n) return;
    ushort8 v = *(const ushort8*)(h + (long)row * 512 + lane * 8);
    float s = 0.f;
#pragma unroll
    for (int e = 0; e < 8; ++e) { float f = bf2f(v[e]); s += f * f; }
    s = wave_sum_dpp(s);
    if (lane == 0) invn[row] = 1.f / fmaxf(sqrtf(s), 1e-12f);
}

// ---- AGNN propagation: bf16 rows, one wave per dst, single-pass -----------
// Fixed-shift softmax: alpha = beta*cos(theta) bounded by |beta|*(1+eps), so
// exp(alpha - 1.0625|beta|) never overflows; shift invariance => exact.
// 2-edge interleave + 4-deep row prefetch + DPP reduce.
__global__ __launch_bounds__(256) void k_agnn(
    const unsigned short* __restrict__ h, const float* __restrict__ invn,
    const int* __restrict__ rowp, const int* __restrict__ col,
    const float* __restrict__ beta_ptr, unsigned short* __restrict__ out,
    float* __restrict__ invn_out, int nNodes) {
    int dst = blockIdx.x * 4 + (threadIdx.x >> 6);
    int lane = threadIdx.x & 63;
    if (dst >= nNodes) return;
    float beta = beta_ptr ? beta_ptr[0] : 1.0f;
    ushort8 hdv = *(const ushort8*)(h + (long)dst * 512 + lane * 8);
    float hd[8];
#pragma unroll
    for (int e = 0; e < 8; ++e) hd[e] = bf2f(hdv[e]);
    float coef = beta * invn[dst];
    float mshift = fabsf(beta) * 1.0625f;   // >= max possible alpha
    int s0 = rowp[dst], s1 = rowp[dst + 1];

    float ssum = 0.f;
    float accE[8] = {0.f, 0.f, 0.f, 0.f, 0.f, 0.f, 0.f, 0.f};
    float accO[8] = {0.f, 0.f, 0.f, 0.f, 0.f, 0.f, 0.f, 0.f};

    for (int base = s0; base < s1; base += 64) {
        int cnt = min(s1 - base, 64);
        int gi = base + lane; if (gi >= s1) gi = s1 - 1;
        int idxl = col[gi];              // batch of up to 64 edge indices
        float vinl = invn[idxl];         // batch of src inv-norms
        ushort8 r0 = {}, r1 = {}, r2 = {}, r3 = {};
        r0 = *(const ushort8*)(h + (long)__builtin_amdgcn_readlane(idxl, 0) * 512 + lane * 8);
        if (cnt > 1) r1 = *(const ushort8*)(h + (long)__builtin_amdgcn_readlane(idxl, 1) * 512 + lane * 8);
        if (cnt > 2) r2 = *(const ushort8*)(h + (long)__builtin_amdgcn_readlane(idxl, 2) * 512 + lane * 8);
        if (cnt > 3) r3 = *(const ushort8*)(h + (long)__builtin_amdgcn_readlane(idxl, 3) * 512 + lane * 8);
        int j = 0;
        for (; j + 1 < cnt; j += 2) {
            ushort8 c0 = r0, c1 = r1;
            r0 = r2; r1 = r3;
            if (j + 4 < cnt) r2 = *(const ushort8*)(h + (long)__builtin_amdgcn_readlane(idxl, j + 4) * 512 + lane * 8);
            if (j + 5 < cnt) r3 = *(const ushort8*)(h + (long)__builtin_amdgcn_readlane(idxl, j + 5) * 512 + lane * 8);
            float a0[8], a1[8];
#pragma unroll
            for (int e = 0; e < 8; ++e) { a0[e] = bf2f(c0[e]); a1[e] = bf2f(c1[e]); }
            float p0 = a0[0] * hd[0] + a0[1] * hd[1] + a0[2] * hd[2] + a0[3] * hd[3] +
                       a0[4] * hd[4] + a0[5] * hd[5] + a0[6] * hd[6] + a0[7] * hd[7];
            float p1 = a1[0] * hd[0] + a1[1] * hd[1] + a1[2] * hd[2] + a1[3] * hd[3] +
                       a1[4] * hd[4] + a1[5] * hd[5] + a1[6] * hd[6] + a1[7] * hd[7];
            p0 = wave_sum_dpp(p0);       // two independent chains interleave
            p1 = wave_sum_dpp(p1);
            float al0 = coef * __int_as_float(__builtin_amdgcn_readlane(__float_as_int(vinl), j)) * p0;
            float al1 = coef * __int_as_float(__builtin_amdgcn_readlane(__float_as_int(vinl), j + 1)) * p1;
            float w0 = __expf(al0 - mshift);
            float w1 = __expf(al1 - mshift);
            ssum += w0 + w1;
#pragma unroll
            for (int e = 0; e < 8; ++e) { accE[e] += w0 * a0[e]; accO[e] += w1 * a1[e]; }
        }
        if (j < cnt) {                   // odd tail
            float a0[8];
#pragma unroll
            for (int e = 0; e < 8; ++e) a0[e] = bf2f(r0[e]);
            float p0 = a0[0] * hd[0] + a0[1] * hd[1] + a0[2] * hd[2] + a0[3] * hd[3] +
                       a0[4] * hd[4] + a0[5] * hd[5] + a0[6] * hd[6] + a0[7] * hd[7];
            p0 = wave_sum_dpp(p0);
            float al0 = coef * __int_as_float(__builtin_amdgcn_readlane(__float_as_int(vinl), j)) * p0;
            float w0 = __expf(al0 - mshift);
            ssum += w0;
#pragma unroll
            for (int e = 0; e < 8; ++e) accE[e] += w0 * a0[e];
        }
    }
    float inv_s = 1.f / ssum;
    float acc[8];
#pragma unroll
    for (int e = 0; e < 8; ++e) acc[e] = (accE[e] + accO[e]) * inv_s;

    uint4v o = { cvtpk(acc[0], acc[1]), cvtpk(acc[2], acc[3]),
                 cvtpk(acc[4], acc[5]), cvtpk(acc[6], acc[7]) };
    *(uint4v*)(out + (long)dst * 512 + lane * 8) = o;

    if (invn_out) {                      // fused output norm (feeds next prop)
        float s = 0.f;
#pragma unroll
        for (int e = 0; e < 8; ++e) s += acc[e] * acc[e];
        s = wave_sum_dpp(s);
        if (lane == 0) invn_out[dst] = 1.f / fmaxf(sqrtf(s), 1e-12f);
    }
}

// ---- per-graph max/mean pool (H2=256), bf16 input, fused bounds -----------
__global__ __launch_bounds__(256) void k_pool(const unsigned short* __restrict__ h3,
                                              const int* __restrict__ batch,
                                              float* __restrict__ pooled, int n) {
    __shared__ int se[2];
    int g = blockIdx.x;
    if (threadIdx.x < 2) {               // binary search graph boundaries
        int tgt = g + (int)threadIdx.x;
        int lo = 0, hi = n;
        while (lo < hi) {
            int mid = (lo + hi) >> 1;
            if (batch[mid] < tgt) lo = mid + 1; else hi = mid;
        }
        se[threadIdx.x] = lo;
    }
    __syncthreads();
    int s = se[0], e = se[1];
    int t = threadIdx.x;
    float mx = -3.402823466e38f, sm = 0.f;
    int r = s;
    for (; r + 4 <= e; r += 4) {          // ILP unroll
        float v0 = bf2f(h3[(long)(r + 0) * 256 + t]);
        float v1 = bf2f(h3[(long)(r + 1) * 256 + t]);
        float v2 = bf2f(h3[(long)(r + 2) * 256 + t]);
        float v3 = bf2f(h3[(long)(r + 3) * 256 + t]);
        mx = fmaxf(mx, fmaxf(fmaxf(v0, v1), fmaxf(v2, v3)));
        sm += (v0 + v1) + (v2 + v3);
    }
    for (; r < e; ++r) {
        float v = bf2f(h3[(long)r * 256 + t]);
        mx = fmaxf(mx, v); sm += v;
    }
    float cnt = fmaxf((float)(e - s), 1.f);
    pooled[g * 512 + t] = mx;
    pooled[g * 512 + 256 + t] = sm / cnt;
}

// ---- final tiny GEMM: out[G][C] = pooled[G][512] @ W3[512][C] + b3 --------
__global__ __launch_bounds__(64) void k_final(const float* __restrict__ pooled,
                                              const float* __restrict__ W3,
                                              const float* __restrict__ b3,
                                              float* __restrict__ out, int C) {
    int g = blockIdx.x;
    int lane = threadIdx.x;
    for (int c = 0; c < C; c++) {
        float p = 0.f;
        for (int k = lane; k < 512; k += 64) p += pooled[g * 512 + k] * W3[k * C + c];
#pragma unroll
        for (int off = 32; off; off >>= 1) p += __shfl_xor(p, off, 64);
        if (lane == 0) out[g * C + c] = p + b3[c];
    }
}

// ---------------------------------------------------------------------------
extern "C" void kernel_launch(void* const* d_in, const int* in_sizes, int n_in,
                              void* d_out, int out_size, void* d_ws, size_t ws_size,
                              hipStream_t stream) {
    const float* x     = (const float*)d_in[0];
    const int*   ei    = (const int*)d_in[1];
    const int*   batch = (const int*)d_in[2];
    const float* W1    = (const float*)d_in[3];
    const float* b1    = (const float*)d_in[4];
    const float* beta2 = (const float*)d_in[5];
    const float* W2    = (const float*)d_in[6];
    const float* b2    = (const float*)d_in[7];
    const float* W3    = (const float*)d_in[8];
    const float* b3    = (const float*)d_in[9];
    float* out = (float*)d_out;

    const int N = in_sizes[2];          // 30000
    const int E = in_sizes[1] / 2;      // 480000
    const int F_IN = in_sizes[0] / N;   // 1280
    const int H = in_sizes[4];          // 512
    const int H2 = in_sizes[7];         // 256
    const int C = in_sizes[9];          // 10
    const int G = out_size / C;         // 64

    char* ws = (char*)d_ws;
    unsigned short* H1B = (unsigned short*)(ws + 0);            // 30.72 MB bf16
    unsigned short* H3B = (unsigned short*)(ws + 0);            // 15.36 MB bf16 (over H1B, dead)
    unsigned short* HPB = (unsigned short*)(ws + 31000000L);    // 30.72 MB bf16
    unsigned short* H2B = (unsigned short*)(ws + 62000000L);    // 30.72 MB bf16
    unsigned short* W1T = (unsigned short*)(ws + 93000000L);    // 1.31 MB
    unsigned short* W2T = (unsigned short*)(ws + 94500000L);    // 0.26 MB
    float* INVN_A = (float*)(ws + 95000000L);                   // 120 KB
    float* INVN_B = (float*)(ws + 95200000L);                   // 120 KB
    int*   CNT    = (int*)(ws + 95400000L);
    int*   FILL   = (int*)(ws + 95600000L);
    int*   ROWP   = (int*)(ws + 95800000L);
    int*   COL    = (int*)(ws + 96000000L);                     // 2.04 MB
    int*   BSUM   = (int*)(ws + 98100000L);
    float* POOLED = (float*)(ws + 98120000L);                   // 131 KB

    // 1. weight transposes (f32 -> bf16 [N][K]) — single launch
    int nt1 = (F_IN / 32) * (H / 32);                // 640
    int nt2 = (H / 32) * (H2 / 32);                  // 128
    k_transpose_both<<<nt1 + nt2, 256, 0, stream>>>(W1, W1T, F_IN, H, nt1,
                                                    W2, W2T, H, H2);

    // 2. CSR (incoming edges + self loops)
    int nb = (N + 1023) / 1024;   // 30
    k_csr_init<<<(N + 255) / 256, 256, 0, stream>>>(CNT, FILL, N);
    k_csr_count<<<(E + 255) / 256, 256, 0, stream>>>(ei, CNT, E);
    k_scan1<<<nb, 1024, 0, stream>>>(CNT, ROWP, BSUM, N);
    k_scan23<<<(N + 1 + 1023) / 1024, 1024, 0, stream>>>(BSUM, ROWP, N, nb);
    k_csr_fill<<<(E + N + 255) / 256, 256, 0, stream>>>(ei, ROWP, FILL, COL, E, N);

    // 3. GEMM1: H1B = bf16(relu(x @ W1 + b1))  [N,512]; 128x256 tiles
    {
        dim3 grid((N + 127) / 128, H / 256);
        k_gemm_bias_relu<1280, 256, 512, true, true>
            <<<grid, 512, 0, stream>>>(x, W1T, b1, H1B, N);
    }

    // 4. prop1 (beta=1): HPB = AGNN(H1B), fused invn of HPB -> INVN_B
    k_norm_bf16<<<(N + 3) / 4, 256, 0, stream>>>(H1B, INVN_A, N);
    k_agnn<<<(N + 3) / 4, 256, 0, stream>>>(H1B, INVN_A, ROWP, COL, nullptr, HPB, INVN_B, N);

    // 5. prop2 (beta=beta2): H2B = AGNN(HPB)
    k_agnn<<<(N + 3) / 4, 256, 0, stream>>>(HPB, INVN_B, ROWP, COL, beta2, H2B, nullptr, N);

    // 6. GEMM2: H3B = bf16(relu(H2B @ W2 + b2))  [N,256]; 128x128 tiles
    {
        dim3 grid((N + 127) / 128, H2 / 128);
        k_gemm_bias_relu<512, 128, 256, false, true>
            <<<grid, 512, 0, stream>>>(H2B, W2T, b2, H3B, N);
    }

    // 7. pool (fused bounds) + final linear
    k_pool<<<G, 256, 0, stream>>>(H3B, batch, POOLED, N);
    k_final<<<G, 64, 0, stream>>>(POOLED, W3, b3, out, C);
}